// Round 18
// baseline (682.586 us; speedup 1.0000x reference)
//
#include <hip/hip_runtime.h>
#include <hip/hip_bf16.h>

typedef __attribute__((ext_vector_type(4))) float f32x4;
typedef __attribute__((ext_vector_type(8))) short short8;
typedef __attribute__((ext_vector_type(4))) int i32x4;
typedef __attribute__((ext_vector_type(2))) unsigned int u32x2;
typedef __attribute__((ext_vector_type(4))) unsigned short u16x4;
typedef __attribute__((ext_vector_type(8))) unsigned short u16x8;

static __device__ __forceinline__ unsigned short f2bf(float f) {
  unsigned u = __builtin_bit_cast(unsigned, f);
  u = u + 0x7FFFu + ((u >> 16) & 1u);   // RNE
  return (unsigned short)(u >> 16);
}
static __device__ __forceinline__ float bf2f(unsigned short b) {
  unsigned u = ((unsigned)b) << 16;
  return __builtin_bit_cast(float, u);
}
static __device__ __forceinline__ float sigmoidf_fast(float x) {
  return __builtin_amdgcn_rcpf(1.f + __expf(-x));
}
// packed bf16 pair: low16 = bf16(a), high16 = bf16(b)
static __device__ __forceinline__ unsigned cvt_pk_bf16(float a, float b) {
  unsigned d;
  asm volatile("v_cvt_pk_bf16_f32 %0, %1, %2" : "=v"(d) : "v"(a), "v"(b));
  return d;
}
// Row-wise (16-lane DPP row) inclusive sum; total lands in lane (lane&15)==15.
static __device__ __forceinline__ float row_sum16(float v) {
  int x;
  x = __builtin_amdgcn_update_dpp(0, __builtin_bit_cast(int, v), 0x111, 0xF, 0xF, true);
  v += __builtin_bit_cast(float, x);   // row_shr:1
  x = __builtin_amdgcn_update_dpp(0, __builtin_bit_cast(int, v), 0x112, 0xF, 0xF, true);
  v += __builtin_bit_cast(float, x);   // row_shr:2
  x = __builtin_amdgcn_update_dpp(0, __builtin_bit_cast(int, v), 0x114, 0xF, 0xF, true);
  v += __builtin_bit_cast(float, x);   // row_shr:4
  x = __builtin_amdgcn_update_dpp(0, __builtin_bit_cast(int, v), 0x118, 0xF, 0xF, true);
  v += __builtin_bit_cast(float, x);   // row_shr:8
  return v;
}
// LDS-only barrier: drains this wave's LDS ops, syncs waves (no vmcnt drain).
static __device__ __forceinline__ void lds_barrier() {
  asm volatile("s_waitcnt lgkmcnt(0)" ::: "memory");
  __builtin_amdgcn_s_barrier();
}
// async global->LDS, 16B per lane: lds dest = uniform base + lane*16.
static __device__ __forceinline__ void gload_lds16(const void* g, void* l) {
  __builtin_amdgcn_global_load_lds(
      (const __attribute__((address_space(1))) void*)g,
      (__attribute__((address_space(3))) void*)l, 16, 0, 0);
}

// ---------------- prep: cast x -> hi/lo bf16 pair AND f gate (fused) ----------------
__global__ __launch_bounds__(256) void prep_kernel(const float* __restrict__ x,
                                                   const float* __restrict__ Wf,
                                                   const float* __restrict__ bfv,
                                                   unsigned short* __restrict__ oh,
                                                   unsigned short* __restrict__ ol,
                                                   float* __restrict__ fbuf) {
  const int tid = threadIdx.x;
  int base = blockIdx.x * 1024;
#pragma unroll
  for (int i = 0; i < 4; ++i) {
    int idx = base + tid + i * 256;
    f32x4 v = ((const f32x4*)x)[idx];
    u16x4 h, l;
#pragma unroll
    for (int j = 0; j < 4; ++j) {
      unsigned short hb = f2bf(v[j]);
      h[j] = hb;
      l[j] = f2bf(v[j] - bf2f(hb));
    }
    ((u16x4*)oh)[idx] = h;
    ((u16x4*)ol)[idx] = l;
  }
  int wid = blockIdx.x * 4 + (tid >> 6);
  int lane = tid & 63;
  const float* xr = x + (size_t)wid * 1024;
  float acc[8] = {0.f, 0.f, 0.f, 0.f, 0.f, 0.f, 0.f, 0.f};
#pragma unroll 4
  for (int it = 0; it < 16; ++it) {
    int d = it * 64 + lane;
    float xv = xr[d];
    f32x4 w0 = *(const f32x4*)(Wf + (size_t)d * 8);
    f32x4 w1 = *(const f32x4*)(Wf + (size_t)d * 8 + 4);
    acc[0] += xv * w0[0]; acc[1] += xv * w0[1];
    acc[2] += xv * w0[2]; acc[3] += xv * w0[3];
    acc[4] += xv * w1[0]; acc[5] += xv * w1[1];
    acc[6] += xv * w1[2]; acc[7] += xv * w1[3];
  }
#pragma unroll
  for (int n = 0; n < 8; ++n) {
#pragma unroll
    for (int m = 1; m < 64; m <<= 1) acc[n] += __shfl_xor(acc[n], m, 64);
  }
  if (lane == 0) {
#pragma unroll
    for (int n = 0; n < 8; ++n)
      fbuf[(size_t)wid * 8 + n] = sigmoidf_fast(acc[n] + bfv[n]);
  }
}

// ---------------- transpose + cast: (R,C) f32 -> (C,R) bf16 ----------------
__global__ void tcast_kernel(const float* __restrict__ in,
                             unsigned short* __restrict__ out, int R, int C) {
  int i = blockIdx.x * blockDim.x + threadIdx.x;
  if (i >= R * C) return;
  int r = i / C, c = i % C;
  out[(size_t)c * R + r] = f2bf(in[i]);
}

// ---------------- transpose + split cast, all 3 weights; 16B vectorized writes ----------------
__global__ void tcast_split3_kernel(const float* __restrict__ Wq,
                                    const float* __restrict__ Wk,
                                    const float* __restrict__ Wv,
                                    unsigned short* __restrict__ oh,
                                    unsigned short* __restrict__ ol) {
  int i = blockIdx.x * 256 + threadIdx.x;          // 0..65535
  int z = blockIdx.y;
  const float* in = (z == 0) ? Wq : (z == 1) ? Wk : Wv;
  int c = i & 511, r8 = i >> 9;                    // c in [0,512), r8 in [0,128)
  u16x8 h, l;
#pragma unroll
  for (int j = 0; j < 8; ++j) {
    float v = in[(size_t)(r8 * 8 + j) * 512 + c];
    unsigned short hb = f2bf(v);
    h[j] = hb;
    l[j] = f2bf(v - bf2f(hb));
  }
  size_t o = (size_t)z * 524288 + (size_t)c * 1024 + r8 * 8;
  *(u16x8*)(oh + o) = h;
  *(u16x8*)(ol + o) = l;
}

// ---------------- causal depthwise conv (KC=4) + SiLU, all 3 tensors ----------------
__global__ void conv_silu_kernel(const float* __restrict__ pre,
                                 const float* __restrict__ cwq,
                                 const float* __restrict__ cwk,
                                 const float* __restrict__ cwv,
                                 float* __restrict__ outb) {
  int i = blockIdx.x * blockDim.x + threadIdx.x;  // B*L*512
  int which = blockIdx.y;
  const float* cw = (which == 0) ? cwq : (which == 1) ? cwk : cwv;
  const float* p = pre + (size_t)which * 2097152 + i;
  int c = i & 511;
  int l = (i >> 9) & 1023;
  float w0 = cw[c * 4 + 0], w1 = cw[c * 4 + 1], w2 = cw[c * 4 + 2], w3 = cw[c * 4 + 3];
  float acc = w3 * p[0];
  if (l >= 1) acc += w2 * p[-512];
  if (l >= 2) acc += w1 * p[-1024];
  if (l >= 3) acc += w0 * p[-1536];
  outb[(size_t)which * 2097152 + i] = acc * sigmoidf_fast(acc);
}

// ---------------- q/k/v pre-activation GEMM with global_load_lds staging ----------------
// z = 0: q, plain 1-term bf16.  z = 1,2: k/v, split-bf16 3-term.
// LDS tiles unpadded [128][32] bf16; staged via global_load_lds width 16:
// wave w issue i covers rows [w*32+i*16, +16); lane l -> row +l/4, col (l&3)*8.
__global__ __launch_bounds__(256) void gemm_qkv_kernel(
    const unsigned short* __restrict__ Ah, const unsigned short* __restrict__ Al,
    const unsigned short* __restrict__ Bth, const unsigned short* __restrict__ Btl,
    float* __restrict__ C) {
  __shared__ unsigned short AshH[128 * 32];
  __shared__ unsigned short AshL[128 * 32];
  __shared__ unsigned short BshH[128 * 32];
  __shared__ unsigned short BshL[128 * 32];
  const int tid = threadIdx.x;
  const int wave = tid >> 6, lane = tid & 63;
  const int g = lane >> 4, lr = lane & 15;
  const int m0 = blockIdx.x * 128, n0 = blockIdx.y * 128;
  const int z = blockIdx.z;
  const bool split = (z != 0);
  const int Kd = 1024;
  const unsigned short* Bzh = Bth + (size_t)z * 524288;
  const unsigned short* Bzl = Btl + (size_t)z * 524288;
  float* Cz = C + (size_t)z * 2097152;
  const int wm = (wave >> 1) * 64, wn = (wave & 1) * 64;
  const int lrow = lane >> 2;            // row within a 16-row staging stripe
  const int lcol = (lane & 3) * 8;       // bf16 col of this lane's 16B

  f32x4 acc[4][4];
#pragma unroll
  for (int a = 0; a < 4; ++a)
#pragma unroll
    for (int bq = 0; bq < 4; ++bq) acc[a][bq] = (f32x4){0.f, 0.f, 0.f, 0.f};

  for (int k0 = 0; k0 < Kd; k0 += 32) {
#pragma unroll
    for (int i = 0; i < 2; ++i) {
      int rbase = wave * 32 + i * 16;                  // uniform per wave
      int ldsoff = rbase * 32;                         // element offset of region
      size_t ga = (size_t)(m0 + rbase + lrow) * Kd + k0 + lcol;
      size_t gb = (size_t)(n0 + rbase + lrow) * Kd + k0 + lcol;
      gload_lds16(Ah + ga, &AshH[ldsoff]);
      gload_lds16(Bzh + gb, &BshH[ldsoff]);
      if (split) {
        gload_lds16(Al + ga, &AshL[ldsoff]);
        gload_lds16(Bzl + gb, &BshL[ldsoff]);
      }
    }
    __syncthreads();   // vmcnt drain: LDS writes landed
    short8 afh[4], bfh[4];
#pragma unroll
    for (int mt = 0; mt < 4; ++mt) afh[mt] = *(const short8*)&AshH[(wm + mt * 16 + lr) * 32 + g * 8];
#pragma unroll
    for (int nt = 0; nt < 4; ++nt) bfh[nt] = *(const short8*)&BshH[(wn + nt * 16 + lr) * 32 + g * 8];
    if (split) {
      short8 afl[4], bfl[4];
#pragma unroll
      for (int mt = 0; mt < 4; ++mt) afl[mt] = *(const short8*)&AshL[(wm + mt * 16 + lr) * 32 + g * 8];
#pragma unroll
      for (int nt = 0; nt < 4; ++nt) bfl[nt] = *(const short8*)&BshL[(wn + nt * 16 + lr) * 32 + g * 8];
#pragma unroll
      for (int mt = 0; mt < 4; ++mt)
#pragma unroll
        for (int nt = 0; nt < 4; ++nt) {
          f32x4 a = acc[mt][nt];
          a = __builtin_amdgcn_mfma_f32_16x16x32_bf16(afl[mt], bfh[nt], a, 0, 0, 0);
          a = __builtin_amdgcn_mfma_f32_16x16x32_bf16(afh[mt], bfl[nt], a, 0, 0, 0);
          a = __builtin_amdgcn_mfma_f32_16x16x32_bf16(afh[mt], bfh[nt], a, 0, 0, 0);
          acc[mt][nt] = a;
        }
    } else {
#pragma unroll
      for (int mt = 0; mt < 4; ++mt)
#pragma unroll
        for (int nt = 0; nt < 4; ++nt)
          acc[mt][nt] = __builtin_amdgcn_mfma_f32_16x16x32_bf16(afh[mt], bfh[nt], acc[mt][nt], 0, 0, 0);
    }
    __syncthreads();   // all frag reads done before next staging overwrites
  }
#pragma unroll
  for (int mt = 0; mt < 4; ++mt)
#pragma unroll
    for (int nt = 0; nt < 4; ++nt)
#pragma unroll
      for (int r = 0; r < 4; ++r) {
        int m = m0 + wm + mt * 16 + g * 4 + r;
        int n = n0 + wn + nt * 16 + lr;
        Cz[(size_t)m * 512 + n] = acc[mt][nt][r];
      }
}

// ---------------- Wo projection GEMM with fused 4-partial y sum ----------------
__global__ __launch_bounds__(256) void gemm_wo_kernel(
    const unsigned short* __restrict__ yp, const unsigned short* __restrict__ Bt,
    float* __restrict__ C) {
  __shared__ unsigned short Ash[128][40];
  __shared__ unsigned short Bsh[128][40];
  const int tid = threadIdx.x;
  const int wave = tid >> 6, lane = tid & 63;
  const int g = lane >> 4, lr = lane & 15;
  const int m0 = blockIdx.x * 128, n0 = blockIdx.y * 128;
  const int Kd = 512, Nd = 1024;
  const int wm = (wave >> 1) * 64, wn = (wave & 1) * 64;

  f32x4 acc[4][4];
#pragma unroll
  for (int a = 0; a < 4; ++a)
#pragma unroll
    for (int bq = 0; bq < 4; ++bq) acc[a][bq] = (f32x4){0.f, 0.f, 0.f, 0.f};

  for (int k0 = 0; k0 < Kd; k0 += 32) {
#pragma unroll
    for (int it = 0; it < 2; ++it) {
      int cch = tid + 256 * it;
      int r = cch >> 2, cc = cch & 3;
      size_t ao = (size_t)(m0 + r) * Kd + k0 + cc * 8;
      u16x4 p0a = *(const u16x4*)(yp + ao);
      u16x4 p0b = *(const u16x4*)(yp + ao + 4);
      u16x4 p1a = *(const u16x4*)(yp + 2097152 + ao);
      u16x4 p1b = *(const u16x4*)(yp + 2097152 + ao + 4);
      u16x4 p2a = *(const u16x4*)(yp + 2 * 2097152 + ao);
      u16x4 p2b = *(const u16x4*)(yp + 2 * 2097152 + ao + 4);
      u16x4 p3a = *(const u16x4*)(yp + 3 * 2097152 + ao);
      u16x4 p3b = *(const u16x4*)(yp + 3 * 2097152 + ao + 4);
      u16x4 sa, sb2;
#pragma unroll
      for (int j = 0; j < 4; ++j) {
        sa[j]  = f2bf(bf2f(p0a[j]) + bf2f(p1a[j]) + bf2f(p2a[j]) + bf2f(p3a[j]));
        sb2[j] = f2bf(bf2f(p0b[j]) + bf2f(p1b[j]) + bf2f(p2b[j]) + bf2f(p3b[j]));
      }
      *(u16x4*)&Ash[r][cc * 8] = sa;
      *(u16x4*)&Ash[r][cc * 8 + 4] = sb2;
      *(i32x4*)&Bsh[r][cc * 8] = *(const i32x4*)(Bt + (size_t)(n0 + r) * Kd + k0 + cc * 8);
    }
    __syncthreads();
    short8 af[4], bfr[4];
#pragma unroll
    for (int mt = 0; mt < 4; ++mt) af[mt] = *(const short8*)&Ash[wm + mt * 16 + lr][g * 8];
#pragma unroll
    for (int nt = 0; nt < 4; ++nt) bfr[nt] = *(const short8*)&Bsh[wn + nt * 16 + lr][g * 8];
#pragma unroll
    for (int mt = 0; mt < 4; ++mt)
#pragma unroll
      for (int nt = 0; nt < 4; ++nt)
        acc[mt][nt] = __builtin_amdgcn_mfma_f32_16x16x32_bf16(af[mt], bfr[nt], acc[mt][nt], 0, 0, 0);
    __syncthreads();
  }
#pragma unroll
  for (int mt = 0; mt < 4; ++mt)
#pragma unroll
    for (int nt = 0; nt < 4; ++nt)
#pragma unroll
      for (int r = 0; r < 4; ++r) {
        int m = m0 + wm + mt * 16 + g * 4 + r;
        int n = n0 + wn + nt * 16 + lr;
        C[(size_t)m * Nd + n] = acc[mt][nt][r];
      }
}

// ---------------- recurrent scan: k-slice split (r11-verified) ----------------
// r18 delta: y pipelined one step behind -- computed at the TOP of the next
// iteration (registers only), filling the post-barrier ds_read latency shadow.
// Chunk epilogue computes the chunk's last y after the tl=15 barrier.
// Slice H planes (ping-pong): row lr at byte lr*128, elem v at (2v)^((lr&7)<<4).
__global__ __launch_bounds__(256) void scan_kernel(
    const float* __restrict__ qbuf, const float* __restrict__ kbuf,
    const float* __restrict__ vbuf, const float* __restrict__ fbuf,
    const float* __restrict__ W, unsigned short* __restrict__ ypart,
    float* __restrict__ Hout) {
  const int tid = threadIdx.x;
  const int wave = tid >> 6, lane = tid & 63;
  const int g = lane >> 4, lr = lane & 15;
  const int bz = blockIdx.x;
  const int chain = bz >> 2, ks = bz & 3;
  const int b = chain >> 3, n = chain & 7;
  const int swz = (lr & 7) << 4;

  __shared__ unsigned short Hh[2][1024];   // 16x64 bf16 hi, ping-pong
  __shared__ unsigned short Hl[2][1024];   // lo planes
  __shared__ float stage[2][16][192];      // 24 KB
  __shared__ float fs[2][16];
  __shared__ float yst[16][64];            // 4 KB

  for (int i = tid; i < 512; i += 256) {
    ((unsigned*)Hh[0])[i] = 0u;
    ((unsigned*)Hl[0])[i] = 0u;
  }

  // W^T split hi/lo fragments: A[m=lr][k-chunk], m = w = 16*wave + lr
  const float* Wn = W + (size_t)n * 4096;
  short8 Af[2], Alw[2];
#pragma unroll
  for (int s = 0; s < 2; ++s) {
    int wcol = wave * 16 + lr;
    short8 ah, al;
#pragma unroll
    for (int j = 0; j < 8; ++j) {
      float wv = Wn[(size_t)(s * 32 + g * 8 + j) * 64 + wcol];
      unsigned short hb = f2bf(wv);
      ah[j] = (short)hb;
      al[j] = (short)f2bf(wv - bf2f(hb));
    }
    Af[s] = ah; Alw[s] = al;
  }

  // chunk staging: 16 steps x 192 floats = 768 f32x4 by 256 threads (3 each)
  auto stage_chunk = [&](int c, int buf) {
#pragma unroll
    for (int i = 0; i < 3; ++i) {
      int fi = tid + i * 256;
      int st = fi / 48, un = fi - st * 48;
      const float* basep = (un < 16) ? qbuf : (un < 32) ? kbuf : vbuf;
      f32x4 val = *(const f32x4*)(basep + (size_t)(b * 1024 + c * 16 + st) * 512 +
                                  n * 64 + (un & 15) * 4);
      *(f32x4*)&stage[buf][st][un * 4] = val;
    }
    if (tid < 16) fs[buf][tid] = fbuf[(size_t)(b * 1024 + c * 16 + tid) * 8 + n];
  };

  f32x4 HA = (f32x4){0.f, 0.f, 0.f, 0.f};  // H[ks*16+lr][w=16*wave+4g+r], f32 master
  int sb = 0, pp = 0;
  float qs_prev = 0.f;

  stage_chunk(0, 0);
  lds_barrier();

  const f32x4 zf = (f32x4){0.f, 0.f, 0.f, 0.f};
  const int bo0 = (16 * g) ^ swz;               // B-frag chunk 0
  const int bo1 = (64 + 16 * g) ^ swz;          // chunk 1
  const int wo = (32 * wave + 8 * g) ^ swz;     // H-write
  const float K2L2E = 2.885390081777927f;       // 2*log2(e)
  const int kg = ks * 16 + lr;                  // global k row of this lane

  for (int c = 0; c < 64; ++c) {
    if (c < 63) stage_chunk(c + 1, sb ^ 1);
    for (int tl = 0; tl < 16; ++tl) {
      const float* srow = &stage[sb][tl][0];

      // B-frags of H_t slice from plane pp (issued first)
      const char* hrh = (const char*)(Hh[pp] + lr * 64);
      const char* hrl = (const char*)(Hl[pp] + lr * 64);
      short8 Bh0 = *(const short8*)(hrh + bo0);
      short8 Bh1 = *(const short8*)(hrh + bo1);
      short8 Bl0 = *(const short8*)(hrl + bo0);
      short8 Bl1 = *(const short8*)(hrl + bo1);

      // pipelined y_{t-1} = q_{t-1} . H_t (registers only; fills ds_read shadow)
      if (tl > 0) {
        float y0 = row_sum16(qs_prev * HA[0]);
        float y1 = row_sum16(qs_prev * HA[1]);
        float y2 = row_sum16(qs_prev * HA[2]);
        float y3 = row_sum16(qs_prev * HA[3]);
        if (lr == 15)
          *(f32x4*)&yst[tl - 1][wave * 16 + 4 * g] = (f32x4){y0, y1, y2, y3};
      }

      float kval = srow[64 + kg];
      f32x4 vv = *(const f32x4*)(srow + 128 + wave * 16 + 4 * g);
      float fc = fs[sb][tl];
      float qs = srow[kg];

      // 6 MFMAs: 3-term split, 2 independent chains of 3
      f32x4 cX = __builtin_amdgcn_mfma_f32_16x16x32_bf16(Alw[0], Bh0, zf, 0, 0, 0);
      f32x4 cY = __builtin_amdgcn_mfma_f32_16x16x32_bf16(Alw[1], Bh1, zf, 0, 0, 0);
      cX = __builtin_amdgcn_mfma_f32_16x16x32_bf16(Af[0], Bl0, cX, 0, 0, 0);
      cY = __builtin_amdgcn_mfma_f32_16x16x32_bf16(Af[1], Bl1, cY, 0, 0, 0);
      cX = __builtin_amdgcn_mfma_f32_16x16x32_bf16(Af[0], Bh0, cX, 0, 0, 0);
      cY = __builtin_amdgcn_mfma_f32_16x16x32_bf16(Af[1], Bh1, cY, 0, 0, 0);

      f32x4 a0 = cX + cY;

      // tanh (exp2-fused, overflow-safe) + gate blend -> H_{t+1} (f32, exact)
#pragma unroll
      for (int r = 0; r < 4; ++r) {
        float arg = fmaf(kval, vv[r], a0[r]);
        float cd = fmaf(-2.f, __builtin_amdgcn_rcpf(1.f + __builtin_amdgcn_exp2f(arg * K2L2E)), 1.f);
        HA[r] = fmaf(fc, HA[r] - cd, cd);
      }

      // pack (cvt_pk) and write H_{t+1} to plane pp^1
      {
        char* hwh = (char*)(Hh[pp ^ 1] + lr * 64);
        char* hwl = (char*)(Hl[pp ^ 1] + lr * 64);
        unsigned ph0 = cvt_pk_bf16(HA[0], HA[1]);
        unsigned ph1 = cvt_pk_bf16(HA[2], HA[3]);
        float r0 = HA[0] - __builtin_bit_cast(float, ph0 << 16);
        float r1 = HA[1] - __builtin_bit_cast(float, ph0 & 0xFFFF0000u);
        float r2 = HA[2] - __builtin_bit_cast(float, ph1 << 16);
        float r3 = HA[3] - __builtin_bit_cast(float, ph1 & 0xFFFF0000u);
        *(u32x2*)(hwh + wo) = (u32x2){ph0, ph1};
        *(u32x2*)(hwl + wo) = (u32x2){cvt_pk_bf16(r0, r1), cvt_pk_bf16(r2, r3)};
      }

      qs_prev = qs;
      lds_barrier();   // LDS-only: plane pp^1 visible
      pp ^= 1;
    }

    // chunk epilogue: y for step c*16+15 (HA = H_{t+1} now)
    {
      float y0 = row_sum16(qs_prev * HA[0]);
      float y1 = row_sum16(qs_prev * HA[1]);
      float y2 = row_sum16(qs_prev * HA[2]);
      float y3 = row_sum16(qs_prev * HA[3]);
      if (lr == 15)
        *(f32x4*)&yst[15][wave * 16 + 4 * g] = (f32x4){y0, y1, y2, y3};
    }
    lds_barrier();   // all yst slots visible for the flush

    // flush y slice-partials for this chunk (bf16), coalesced
    for (int i = tid; i < 1024; i += 256) {
      int tl2 = i >> 6, w = i & 63;
      ypart[(size_t)ks * 2097152 +
            (size_t)(b * 1024 + c * 16 + tl2) * 512 + n * 64 + w] = f2bf(yst[tl2][w]);
    }
    lds_barrier();   // protect yst reuse by next chunk
    sb ^= 1;
  }

  // H_final (f32 master): this slice owns rows ks*16..ks*16+16
  float* Ho = Hout + (size_t)(b * 8 + n) * 4096;
  *(f32x4*)&Ho[(size_t)kg * 64 + wave * 16 + g * 4] = HA;
}

// ---------------- launch ----------------
extern "C" void kernel_launch(void* const* d_in, const int* in_sizes, int n_in,
                              void* d_out, int out_size, void* d_ws, size_t ws_size,
                              hipStream_t stream) {
  const float* x   = (const float*)d_in[0];
  const float* Wq  = (const float*)d_in[1];
  const float* Wk  = (const float*)d_in[2];
  const float* Wv  = (const float*)d_in[3];
  const float* Wf  = (const float*)d_in[4];
  const float* bfv = (const float*)d_in[5];
  const float* cwq = (const float*)d_in[6];
  const float* cwk = (const float*)d_in[7];
  const float* cwv = (const float*)d_in[8];
  const float* W   = (const float*)d_in[9];
  const float* Wo  = (const float*)d_in[10];
  float* outp = (float*)d_out;

  char* ws = (char*)d_ws;
  size_t off = 0;
  auto alloc = [&](size_t bytes) {
    char* pp = ws + off;
    off = (off + bytes + 255) & ~(size_t)255;
    return pp;
  };
  unsigned short* xbh  = (unsigned short*)alloc((size_t)4194304 * 2);
  unsigned short* xbl  = (unsigned short*)alloc((size_t)4194304 * 2);
  unsigned short* wtbh = (unsigned short*)alloc((size_t)3 * 524288 * 2);
  unsigned short* wtbl = (unsigned short*)alloc((size_t)3 * 524288 * 2);
  float* pre  = (float*)alloc((size_t)3 * 2097152 * 4);   // aliased: y partials
  float* qkv  = (float*)alloc((size_t)3 * 2097152 * 4);
  float* fbuf = (float*)alloc((size_t)32768 * 4);
  unsigned short* wot = (unsigned short*)alloc((size_t)524288 * 2);
  unsigned short* ypart = (unsigned short*)pre;  // pre is dead after conv_silu

  // prep: cast x (hi/lo) + f gate, fused
  prep_kernel<<<1024, 256, 0, stream>>>(x, Wf, bfv, xbh, xbl, fbuf);
  // weight transposes (split hi/lo), vectorized writes
  dim3 gt(256, 3, 1);
  tcast_split3_kernel<<<gt, 256, 0, stream>>>(Wq, Wk, Wv, wtbh, wtbl);
  // q/k/v pre-activations in ONE dispatch (z=0 plain, z=1,2 split)
  dim3 g1(32, 4, 3);
  gemm_qkv_kernel<<<g1, 256, 0, stream>>>(xbh, xbl, wtbh, wtbl, pre);
  // conv + silu (all three in one launch); pre is dead afterwards
  dim3 gc(8192, 3, 1);
  conv_silu_kernel<<<gc, 256, 0, stream>>>(pre, cwq, cwk, cwv, qkv);
  // recurrent scan: 128 blocks (32 chains x 4 k-slices) x 256 threads
  scan_kernel<<<128, 256, 0, stream>>>(qkv, qkv + 2097152, qkv + 2 * 2097152, fbuf, W,
                                       ypart, outp + 4194304);
  // output projection with fused 4-partial y sum
  tcast_kernel<<<2048, 256, 0, stream>>>(Wo, wot, 512, 1024);
  dim3 g2(32, 8, 1);
  gemm_wo_kernel<<<g2, 256, 0, stream>>>(ypart, wot, outp);
}

// Round 19
// 638.027 us; speedup vs baseline: 1.0698x; 1.0698x over previous
//
#include <hip/hip_runtime.h>
#include <hip/hip_bf16.h>

typedef __attribute__((ext_vector_type(4))) float f32x4;
typedef __attribute__((ext_vector_type(8))) short short8;
typedef __attribute__((ext_vector_type(4))) int i32x4;
typedef __attribute__((ext_vector_type(2))) unsigned int u32x2;
typedef __attribute__((ext_vector_type(4))) unsigned short u16x4;
typedef __attribute__((ext_vector_type(8))) unsigned short u16x8;

static __device__ __forceinline__ unsigned short f2bf(float f) {
  unsigned u = __builtin_bit_cast(unsigned, f);
  u = u + 0x7FFFu + ((u >> 16) & 1u);   // RNE
  return (unsigned short)(u >> 16);
}
static __device__ __forceinline__ float bf2f(unsigned short b) {
  unsigned u = ((unsigned)b) << 16;
  return __builtin_bit_cast(float, u);
}
static __device__ __forceinline__ float sigmoidf_fast(float x) {
  return __builtin_amdgcn_rcpf(1.f + __expf(-x));
}
// packed bf16 pair: low16 = bf16(a), high16 = bf16(b)
static __device__ __forceinline__ unsigned cvt_pk_bf16(float a, float b) {
  unsigned d;
  asm volatile("v_cvt_pk_bf16_f32 %0, %1, %2" : "=v"(d) : "v"(a), "v"(b));
  return d;
}
// Row-wise (16-lane DPP row) inclusive sum; total lands in lane (lane&15)==15.
static __device__ __forceinline__ float row_sum16(float v) {
  int x;
  x = __builtin_amdgcn_update_dpp(0, __builtin_bit_cast(int, v), 0x111, 0xF, 0xF, true);
  v += __builtin_bit_cast(float, x);   // row_shr:1
  x = __builtin_amdgcn_update_dpp(0, __builtin_bit_cast(int, v), 0x112, 0xF, 0xF, true);
  v += __builtin_bit_cast(float, x);   // row_shr:2
  x = __builtin_amdgcn_update_dpp(0, __builtin_bit_cast(int, v), 0x114, 0xF, 0xF, true);
  v += __builtin_bit_cast(float, x);   // row_shr:4
  x = __builtin_amdgcn_update_dpp(0, __builtin_bit_cast(int, v), 0x118, 0xF, 0xF, true);
  v += __builtin_bit_cast(float, x);   // row_shr:8
  return v;
}
// LDS-only barrier: drains this wave's LDS ops, syncs waves (no vmcnt drain).
static __device__ __forceinline__ void lds_barrier() {
  asm volatile("s_waitcnt lgkmcnt(0)" ::: "memory");
  __builtin_amdgcn_s_barrier();
}
// async global->LDS, 16B per lane: lds dest = uniform base + lane*16.
static __device__ __forceinline__ void gload_lds16(const void* g, void* l) {
  __builtin_amdgcn_global_load_lds(
      (const __attribute__((address_space(1))) void*)g,
      (__attribute__((address_space(3))) void*)l, 16, 0, 0);
}

// ---------------- prep: cast x -> hi/lo bf16 pair AND f gate (fused) ----------------
__global__ __launch_bounds__(256) void prep_kernel(const float* __restrict__ x,
                                                   const float* __restrict__ Wf,
                                                   const float* __restrict__ bfv,
                                                   unsigned short* __restrict__ oh,
                                                   unsigned short* __restrict__ ol,
                                                   float* __restrict__ fbuf) {
  const int tid = threadIdx.x;
  int base = blockIdx.x * 1024;
#pragma unroll
  for (int i = 0; i < 4; ++i) {
    int idx = base + tid + i * 256;
    f32x4 v = ((const f32x4*)x)[idx];
    u16x4 h, l;
#pragma unroll
    for (int j = 0; j < 4; ++j) {
      unsigned short hb = f2bf(v[j]);
      h[j] = hb;
      l[j] = f2bf(v[j] - bf2f(hb));
    }
    ((u16x4*)oh)[idx] = h;
    ((u16x4*)ol)[idx] = l;
  }
  int wid = blockIdx.x * 4 + (tid >> 6);
  int lane = tid & 63;
  const float* xr = x + (size_t)wid * 1024;
  float acc[8] = {0.f, 0.f, 0.f, 0.f, 0.f, 0.f, 0.f, 0.f};
#pragma unroll 4
  for (int it = 0; it < 16; ++it) {
    int d = it * 64 + lane;
    float xv = xr[d];
    f32x4 w0 = *(const f32x4*)(Wf + (size_t)d * 8);
    f32x4 w1 = *(const f32x4*)(Wf + (size_t)d * 8 + 4);
    acc[0] += xv * w0[0]; acc[1] += xv * w0[1];
    acc[2] += xv * w0[2]; acc[3] += xv * w0[3];
    acc[4] += xv * w1[0]; acc[5] += xv * w1[1];
    acc[6] += xv * w1[2]; acc[7] += xv * w1[3];
  }
#pragma unroll
  for (int n = 0; n < 8; ++n) {
#pragma unroll
    for (int m = 1; m < 64; m <<= 1) acc[n] += __shfl_xor(acc[n], m, 64);
  }
  if (lane == 0) {
#pragma unroll
    for (int n = 0; n < 8; ++n)
      fbuf[(size_t)wid * 8 + n] = sigmoidf_fast(acc[n] + bfv[n]);
  }
}

// ---------------- transpose + cast: (R,C) f32 -> (C,R) bf16 ----------------
__global__ void tcast_kernel(const float* __restrict__ in,
                             unsigned short* __restrict__ out, int R, int C) {
  int i = blockIdx.x * blockDim.x + threadIdx.x;
  if (i >= R * C) return;
  int r = i / C, c = i % C;
  out[(size_t)c * R + r] = f2bf(in[i]);
}

// ---------------- transpose + split cast, all 3 weights; 16B vectorized writes ----------------
__global__ void tcast_split3_kernel(const float* __restrict__ Wq,
                                    const float* __restrict__ Wk,
                                    const float* __restrict__ Wv,
                                    unsigned short* __restrict__ oh,
                                    unsigned short* __restrict__ ol) {
  int i = blockIdx.x * 256 + threadIdx.x;          // 0..65535
  int z = blockIdx.y;
  const float* in = (z == 0) ? Wq : (z == 1) ? Wk : Wv;
  int c = i & 511, r8 = i >> 9;                    // c in [0,512), r8 in [0,128)
  u16x8 h, l;
#pragma unroll
  for (int j = 0; j < 8; ++j) {
    float v = in[(size_t)(r8 * 8 + j) * 512 + c];
    unsigned short hb = f2bf(v);
    h[j] = hb;
    l[j] = f2bf(v - bf2f(hb));
  }
  size_t o = (size_t)z * 524288 + (size_t)c * 1024 + r8 * 8;
  *(u16x8*)(oh + o) = h;
  *(u16x8*)(ol + o) = l;
}

// ---------------- causal depthwise conv (KC=4) + SiLU, all 3 tensors ----------------
__global__ void conv_silu_kernel(const float* __restrict__ pre,
                                 const float* __restrict__ cwq,
                                 const float* __restrict__ cwk,
                                 const float* __restrict__ cwv,
                                 float* __restrict__ outb) {
  int i = blockIdx.x * blockDim.x + threadIdx.x;  // B*L*512
  int which = blockIdx.y;
  const float* cw = (which == 0) ? cwq : (which == 1) ? cwk : cwv;
  const float* p = pre + (size_t)which * 2097152 + i;
  int c = i & 511;
  int l = (i >> 9) & 1023;
  float w0 = cw[c * 4 + 0], w1 = cw[c * 4 + 1], w2 = cw[c * 4 + 2], w3 = cw[c * 4 + 3];
  float acc = w3 * p[0];
  if (l >= 1) acc += w2 * p[-512];
  if (l >= 2) acc += w1 * p[-1024];
  if (l >= 3) acc += w0 * p[-1536];
  outb[(size_t)which * 2097152 + i] = acc * sigmoidf_fast(acc);
}

// ---------------- q/k/v pre-activation GEMM with global_load_lds staging ----------------
// z = 0: q, plain 1-term bf16.  z = 1,2: k/v, split-bf16 3-term.
// LDS tiles unpadded [128][32] bf16; staged via global_load_lds width 16:
// wave w issue i covers rows [w*32+i*16, +16); lane l -> row +l/4, col (l&3)*8.
__global__ __launch_bounds__(256) void gemm_qkv_kernel(
    const unsigned short* __restrict__ Ah, const unsigned short* __restrict__ Al,
    const unsigned short* __restrict__ Bth, const unsigned short* __restrict__ Btl,
    float* __restrict__ C) {
  __shared__ unsigned short AshH[128 * 32];
  __shared__ unsigned short AshL[128 * 32];
  __shared__ unsigned short BshH[128 * 32];
  __shared__ unsigned short BshL[128 * 32];
  const int tid = threadIdx.x;
  const int wave = tid >> 6, lane = tid & 63;
  const int g = lane >> 4, lr = lane & 15;
  const int m0 = blockIdx.x * 128, n0 = blockIdx.y * 128;
  const int z = blockIdx.z;
  const bool split = (z != 0);
  const int Kd = 1024;
  const unsigned short* Bzh = Bth + (size_t)z * 524288;
  const unsigned short* Bzl = Btl + (size_t)z * 524288;
  float* Cz = C + (size_t)z * 2097152;
  const int wm = (wave >> 1) * 64, wn = (wave & 1) * 64;
  const int lrow = lane >> 2;            // row within a 16-row staging stripe
  const int lcol = (lane & 3) * 8;       // bf16 col of this lane's 16B

  f32x4 acc[4][4];
#pragma unroll
  for (int a = 0; a < 4; ++a)
#pragma unroll
    for (int bq = 0; bq < 4; ++bq) acc[a][bq] = (f32x4){0.f, 0.f, 0.f, 0.f};

  for (int k0 = 0; k0 < Kd; k0 += 32) {
#pragma unroll
    for (int i = 0; i < 2; ++i) {
      int rbase = wave * 32 + i * 16;                  // uniform per wave
      int ldsoff = rbase * 32;                         // element offset of region
      size_t ga = (size_t)(m0 + rbase + lrow) * Kd + k0 + lcol;
      size_t gb = (size_t)(n0 + rbase + lrow) * Kd + k0 + lcol;
      gload_lds16(Ah + ga, &AshH[ldsoff]);
      gload_lds16(Bzh + gb, &BshH[ldsoff]);
      if (split) {
        gload_lds16(Al + ga, &AshL[ldsoff]);
        gload_lds16(Bzl + gb, &BshL[ldsoff]);
      }
    }
    __syncthreads();   // vmcnt drain: LDS writes landed
    short8 afh[4], bfh[4];
#pragma unroll
    for (int mt = 0; mt < 4; ++mt) afh[mt] = *(const short8*)&AshH[(wm + mt * 16 + lr) * 32 + g * 8];
#pragma unroll
    for (int nt = 0; nt < 4; ++nt) bfh[nt] = *(const short8*)&BshH[(wn + nt * 16 + lr) * 32 + g * 8];
    if (split) {
      short8 afl[4], bfl[4];
#pragma unroll
      for (int mt = 0; mt < 4; ++mt) afl[mt] = *(const short8*)&AshL[(wm + mt * 16 + lr) * 32 + g * 8];
#pragma unroll
      for (int nt = 0; nt < 4; ++nt) bfl[nt] = *(const short8*)&BshL[(wn + nt * 16 + lr) * 32 + g * 8];
#pragma unroll
      for (int mt = 0; mt < 4; ++mt)
#pragma unroll
        for (int nt = 0; nt < 4; ++nt) {
          f32x4 a = acc[mt][nt];
          a = __builtin_amdgcn_mfma_f32_16x16x32_bf16(afl[mt], bfh[nt], a, 0, 0, 0);
          a = __builtin_amdgcn_mfma_f32_16x16x32_bf16(afh[mt], bfl[nt], a, 0, 0, 0);
          a = __builtin_amdgcn_mfma_f32_16x16x32_bf16(afh[mt], bfh[nt], a, 0, 0, 0);
          acc[mt][nt] = a;
        }
    } else {
#pragma unroll
      for (int mt = 0; mt < 4; ++mt)
#pragma unroll
        for (int nt = 0; nt < 4; ++nt)
          acc[mt][nt] = __builtin_amdgcn_mfma_f32_16x16x32_bf16(afh[mt], bfh[nt], acc[mt][nt], 0, 0, 0);
    }
    __syncthreads();   // all frag reads done before next staging overwrites
  }
#pragma unroll
  for (int mt = 0; mt < 4; ++mt)
#pragma unroll
    for (int nt = 0; nt < 4; ++nt)
#pragma unroll
      for (int r = 0; r < 4; ++r) {
        int m = m0 + wm + mt * 16 + g * 4 + r;
        int n = n0 + wn + nt * 16 + lr;
        Cz[(size_t)m * 512 + n] = acc[mt][nt][r];
      }
}

// ---------------- Wo projection GEMM with fused 4-partial y sum ----------------
__global__ __launch_bounds__(256) void gemm_wo_kernel(
    const unsigned short* __restrict__ yp, const unsigned short* __restrict__ Bt,
    float* __restrict__ C) {
  __shared__ unsigned short Ash[128][40];
  __shared__ unsigned short Bsh[128][40];
  const int tid = threadIdx.x;
  const int wave = tid >> 6, lane = tid & 63;
  const int g = lane >> 4, lr = lane & 15;
  const int m0 = blockIdx.x * 128, n0 = blockIdx.y * 128;
  const int Kd = 512, Nd = 1024;
  const int wm = (wave >> 1) * 64, wn = (wave & 1) * 64;

  f32x4 acc[4][4];
#pragma unroll
  for (int a = 0; a < 4; ++a)
#pragma unroll
    for (int bq = 0; bq < 4; ++bq) acc[a][bq] = (f32x4){0.f, 0.f, 0.f, 0.f};

  for (int k0 = 0; k0 < Kd; k0 += 32) {
#pragma unroll
    for (int it = 0; it < 2; ++it) {
      int cch = tid + 256 * it;
      int r = cch >> 2, cc = cch & 3;
      size_t ao = (size_t)(m0 + r) * Kd + k0 + cc * 8;
      u16x4 p0a = *(const u16x4*)(yp + ao);
      u16x4 p0b = *(const u16x4*)(yp + ao + 4);
      u16x4 p1a = *(const u16x4*)(yp + 2097152 + ao);
      u16x4 p1b = *(const u16x4*)(yp + 2097152 + ao + 4);
      u16x4 p2a = *(const u16x4*)(yp + 2 * 2097152 + ao);
      u16x4 p2b = *(const u16x4*)(yp + 2 * 2097152 + ao + 4);
      u16x4 p3a = *(const u16x4*)(yp + 3 * 2097152 + ao);
      u16x4 p3b = *(const u16x4*)(yp + 3 * 2097152 + ao + 4);
      u16x4 sa, sb2;
#pragma unroll
      for (int j = 0; j < 4; ++j) {
        sa[j]  = f2bf(bf2f(p0a[j]) + bf2f(p1a[j]) + bf2f(p2a[j]) + bf2f(p3a[j]));
        sb2[j] = f2bf(bf2f(p0b[j]) + bf2f(p1b[j]) + bf2f(p2b[j]) + bf2f(p3b[j]));
      }
      *(u16x4*)&Ash[r][cc * 8] = sa;
      *(u16x4*)&Ash[r][cc * 8 + 4] = sb2;
      *(i32x4*)&Bsh[r][cc * 8] = *(const i32x4*)(Bt + (size_t)(n0 + r) * Kd + k0 + cc * 8);
    }
    __syncthreads();
    short8 af[4], bfr[4];
#pragma unroll
    for (int mt = 0; mt < 4; ++mt) af[mt] = *(const short8*)&Ash[wm + mt * 16 + lr][g * 8];
#pragma unroll
    for (int nt = 0; nt < 4; ++nt) bfr[nt] = *(const short8*)&Bsh[wn + nt * 16 + lr][g * 8];
#pragma unroll
    for (int mt = 0; mt < 4; ++mt)
#pragma unroll
      for (int nt = 0; nt < 4; ++nt)
        acc[mt][nt] = __builtin_amdgcn_mfma_f32_16x16x32_bf16(af[mt], bfr[nt], acc[mt][nt], 0, 0, 0);
    __syncthreads();
  }
#pragma unroll
  for (int mt = 0; mt < 4; ++mt)
#pragma unroll
    for (int nt = 0; nt < 4; ++nt)
#pragma unroll
      for (int r = 0; r < 4; ++r) {
        int m = m0 + wm + mt * 16 + g * 4 + r;
        int n = n0 + wn + nt * 16 + lr;
        C[(size_t)m * Nd + n] = acc[mt][nt][r];
      }
}

// ---------------- recurrent scan: k-slice split (r17-verified ordering) ----------------
// Order per step: B-frag reads -> MFMAs -> tanh+blend -> H pack+write -> y-DPP
// (covers the ds_write drain) -> lds_barrier. No cross-step y pipelining (r18
// regressed: it exposed the write drain at the barrier).
// Slice H planes (ping-pong): row lr at byte lr*128, elem v at (2v)^((lr&7)<<4).
__global__ __launch_bounds__(256) void scan_kernel(
    const float* __restrict__ qbuf, const float* __restrict__ kbuf,
    const float* __restrict__ vbuf, const float* __restrict__ fbuf,
    const float* __restrict__ W, unsigned short* __restrict__ ypart,
    float* __restrict__ Hout) {
  const int tid = threadIdx.x;
  const int wave = tid >> 6, lane = tid & 63;
  const int g = lane >> 4, lr = lane & 15;
  const int bz = blockIdx.x;
  const int chain = bz >> 2, ks = bz & 3;
  const int b = chain >> 3, n = chain & 7;
  const int swz = (lr & 7) << 4;

  __shared__ unsigned short Hh[2][1024];   // 16x64 bf16 hi, ping-pong
  __shared__ unsigned short Hl[2][1024];   // lo planes
  __shared__ float stage[2][16][192];      // 24 KB
  __shared__ float fs[2][16];
  __shared__ float yst[16][64];            // 4 KB

  for (int i = tid; i < 512; i += 256) {
    ((unsigned*)Hh[0])[i] = 0u;
    ((unsigned*)Hl[0])[i] = 0u;
  }

  // W^T split hi/lo fragments: A[m=lr][k-chunk], m = w = 16*wave + lr
  const float* Wn = W + (size_t)n * 4096;
  short8 Af[2], Alw[2];
#pragma unroll
  for (int s = 0; s < 2; ++s) {
    int wcol = wave * 16 + lr;
    short8 ah, al;
#pragma unroll
    for (int j = 0; j < 8; ++j) {
      float wv = Wn[(size_t)(s * 32 + g * 8 + j) * 64 + wcol];
      unsigned short hb = f2bf(wv);
      ah[j] = (short)hb;
      al[j] = (short)f2bf(wv - bf2f(hb));
    }
    Af[s] = ah; Alw[s] = al;
  }

  // chunk staging: 16 steps x 192 floats = 768 f32x4 by 256 threads (3 each)
  auto stage_chunk = [&](int c, int buf) {
#pragma unroll
    for (int i = 0; i < 3; ++i) {
      int fi = tid + i * 256;
      int st = fi / 48, un = fi - st * 48;
      const float* basep = (un < 16) ? qbuf : (un < 32) ? kbuf : vbuf;
      f32x4 val = *(const f32x4*)(basep + (size_t)(b * 1024 + c * 16 + st) * 512 +
                                  n * 64 + (un & 15) * 4);
      *(f32x4*)&stage[buf][st][un * 4] = val;
    }
    if (tid < 16) fs[buf][tid] = fbuf[(size_t)(b * 1024 + c * 16 + tid) * 8 + n];
  };

  f32x4 HA = (f32x4){0.f, 0.f, 0.f, 0.f};  // H[ks*16+lr][w=16*wave+4g+r], f32 master
  int sb = 0, pp = 0;

  stage_chunk(0, 0);
  lds_barrier();

  const f32x4 zf = (f32x4){0.f, 0.f, 0.f, 0.f};
  const int bo0 = (16 * g) ^ swz;               // B-frag chunk 0
  const int bo1 = (64 + 16 * g) ^ swz;          // chunk 1
  const int wo = (32 * wave + 8 * g) ^ swz;     // H-write
  const float K2L2E = 2.885390081777927f;       // 2*log2(e)
  const int kg = ks * 16 + lr;                  // global k row of this lane

  for (int c = 0; c < 64; ++c) {
    if (c < 63) stage_chunk(c + 1, sb ^ 1);
    for (int tl = 0; tl < 16; ++tl) {
      const float* srow = &stage[sb][tl][0];

      // B-frags of H_t slice from plane pp
      const char* hrh = (const char*)(Hh[pp] + lr * 64);
      const char* hrl = (const char*)(Hl[pp] + lr * 64);
      short8 Bh0 = *(const short8*)(hrh + bo0);
      short8 Bh1 = *(const short8*)(hrh + bo1);
      short8 Bl0 = *(const short8*)(hrl + bo0);
      short8 Bl1 = *(const short8*)(hrl + bo1);

      // 6 MFMAs: 3-term split, 2 independent chains of 3
      f32x4 cX = __builtin_amdgcn_mfma_f32_16x16x32_bf16(Alw[0], Bh0, zf, 0, 0, 0);
      f32x4 cY = __builtin_amdgcn_mfma_f32_16x16x32_bf16(Alw[1], Bh1, zf, 0, 0, 0);
      cX = __builtin_amdgcn_mfma_f32_16x16x32_bf16(Af[0], Bl0, cX, 0, 0, 0);
      cY = __builtin_amdgcn_mfma_f32_16x16x32_bf16(Af[1], Bl1, cY, 0, 0, 0);
      cX = __builtin_amdgcn_mfma_f32_16x16x32_bf16(Af[0], Bh0, cX, 0, 0, 0);
      cY = __builtin_amdgcn_mfma_f32_16x16x32_bf16(Af[1], Bh1, cY, 0, 0, 0);

      float kval = srow[64 + kg];
      f32x4 vv = *(const f32x4*)(srow + 128 + wave * 16 + 4 * g);
      float fc = fs[sb][tl];
      f32x4 a0 = cX + cY;

      // tanh (exp2-fused, overflow-safe) + gate blend -> H_{t+1} (f32, exact)
#pragma unroll
      for (int r = 0; r < 4; ++r) {
        float arg = fmaf(kval, vv[r], a0[r]);
        float cd = fmaf(-2.f, __builtin_amdgcn_rcpf(1.f + __builtin_amdgcn_exp2f(arg * K2L2E)), 1.f);
        HA[r] = fmaf(fc, HA[r] - cd, cd);
      }

      // pack (cvt_pk) and write H_{t+1} to plane pp^1 FIRST (retires under y-VALU)
      {
        char* hwh = (char*)(Hh[pp ^ 1] + lr * 64);
        char* hwl = (char*)(Hl[pp ^ 1] + lr * 64);
        unsigned ph0 = cvt_pk_bf16(HA[0], HA[1]);
        unsigned ph1 = cvt_pk_bf16(HA[2], HA[3]);
        float r0 = HA[0] - __builtin_bit_cast(float, ph0 << 16);
        float r1 = HA[1] - __builtin_bit_cast(float, ph0 & 0xFFFF0000u);
        float r2 = HA[2] - __builtin_bit_cast(float, ph1 << 16);
        float r3 = HA[3] - __builtin_bit_cast(float, ph1 & 0xFFFF0000u);
        *(u32x2*)(hwh + wo) = (u32x2){ph0, ph1};
        *(u32x2*)(hwl + wo) = (u32x2){cvt_pk_bf16(r0, r1), cvt_pk_bf16(r2, r3)};
      }

      // y slice-partials: DPP row-sum over the 16 k-lanes (VALU covers the writes)
      {
        float qs = srow[kg];
        float y0 = row_sum16(qs * HA[0]);
        float y1 = row_sum16(qs * HA[1]);
        float y2 = row_sum16(qs * HA[2]);
        float y3 = row_sum16(qs * HA[3]);
        if (lr == 15)
          *(f32x4*)&yst[tl][wave * 16 + 4 * g] = (f32x4){y0, y1, y2, y3};
      }

      lds_barrier();   // LDS-only: plane pp^1 + yst visible, no vmcnt drain
      pp ^= 1;
    }

    // flush y slice-partials for this chunk (bf16), coalesced
    for (int i = tid; i < 1024; i += 256) {
      int tl2 = i >> 6, w = i & 63;
      ypart[(size_t)ks * 2097152 +
            (size_t)(b * 1024 + c * 16 + tl2) * 512 + n * 64 + w] = f2bf(yst[tl2][w]);
    }
    lds_barrier();   // protect yst reuse by next chunk
    sb ^= 1;
  }

  // H_final (f32 master): this slice owns rows ks*16..ks*16+16
  float* Ho = Hout + (size_t)(b * 8 + n) * 4096;
  *(f32x4*)&Ho[(size_t)kg * 64 + wave * 16 + g * 4] = HA;
}

// ---------------- launch ----------------
extern "C" void kernel_launch(void* const* d_in, const int* in_sizes, int n_in,
                              void* d_out, int out_size, void* d_ws, size_t ws_size,
                              hipStream_t stream) {
  const float* x   = (const float*)d_in[0];
  const float* Wq  = (const float*)d_in[1];
  const float* Wk  = (const float*)d_in[2];
  const float* Wv  = (const float*)d_in[3];
  const float* Wf  = (const float*)d_in[4];
  const float* bfv = (const float*)d_in[5];
  const float* cwq = (const float*)d_in[6];
  const float* cwk = (const float*)d_in[7];
  const float* cwv = (const float*)d_in[8];
  const float* W   = (const float*)d_in[9];
  const float* Wo  = (const float*)d_in[10];
  float* outp = (float*)d_out;

  char* ws = (char*)d_ws;
  size_t off = 0;
  auto alloc = [&](size_t bytes) {
    char* pp = ws + off;
    off = (off + bytes + 255) & ~(size_t)255;
    return pp;
  };
  unsigned short* xbh  = (unsigned short*)alloc((size_t)4194304 * 2);
  unsigned short* xbl  = (unsigned short*)alloc((size_t)4194304 * 2);
  unsigned short* wtbh = (unsigned short*)alloc((size_t)3 * 524288 * 2);
  unsigned short* wtbl = (unsigned short*)alloc((size_t)3 * 524288 * 2);
  float* pre  = (float*)alloc((size_t)3 * 2097152 * 4);   // aliased: y partials
  float* qkv  = (float*)alloc((size_t)3 * 2097152 * 4);
  float* fbuf = (float*)alloc((size_t)32768 * 4);
  unsigned short* wot = (unsigned short*)alloc((size_t)524288 * 2);
  unsigned short* ypart = (unsigned short*)pre;  // pre is dead after conv_silu

  // prep: cast x (hi/lo) + f gate, fused
  prep_kernel<<<1024, 256, 0, stream>>>(x, Wf, bfv, xbh, xbl, fbuf);
  // weight transposes (split hi/lo), vectorized writes
  dim3 gt(256, 3, 1);
  tcast_split3_kernel<<<gt, 256, 0, stream>>>(Wq, Wk, Wv, wtbh, wtbl);
  // q/k/v pre-activations in ONE dispatch (z=0 plain, z=1,2 split)
  dim3 g1(32, 4, 3);
  gemm_qkv_kernel<<<g1, 256, 0, stream>>>(xbh, xbl, wtbh, wtbl, pre);
  // conv + silu (all three in one launch); pre is dead afterwards
  dim3 gc(8192, 3, 1);
  conv_silu_kernel<<<gc, 256, 0, stream>>>(pre, cwq, cwk, cwv, qkv);
  // recurrent scan: 128 blocks (32 chains x 4 k-slices) x 256 threads
  scan_kernel<<<128, 256, 0, stream>>>(qkv, qkv + 2097152, qkv + 2 * 2097152, fbuf, W,
                                       ypart, outp + 4194304);
  // output projection with fused 4-partial y sum
  tcast_kernel<<<2048, 256, 0, stream>>>(Wo, wot, 512, 1024);
  dim3 g2(32, 8, 1);
  gemm_wo_kernel<<<g2, 256, 0, stream>>>(ypart, wot, outp);
}